// Round 12
// baseline (198.327 us; speedup 1.0000x reference)
//
#include <hip/hip_runtime.h>

// CTC forward loss, B=256, T=1024, C=128, L=64, S=2L+1=129, BLANK=127.
// Round 20: SPLIT-BLOCK BISECTION (2 kernels).
// Model fitting R11-R19: kernel time = TOTAL dynamic instrs aggregated
// across a CU's resident waves x ~3.8ns (~9.1 cyc) -- deps, I$, and
// same-block wave count all irrelevant (R19: two co-resident waves, half
// steps each, EXACTLY zero gain). Discriminator: put the two halves in
// SEPARATE BLOCKS. 512 blocks round-robin across XCDs -> paired halves on
// different CUs; if the ~9cyc/instr cadence is per-SIMD (or per-CU but now
// spread over 2x CUs... 512 blocks/256 CUs = 2 blocks/CU from DIFFERENT
// elements -- distinguishes per-CU-aggregate vs per-wave placement).
//   kernel 1 (ctc_halves, 512 x 64): block 2b = verified forward half
//     (rows 0..511 -> alpha_511); block 2b+1 = verified reversed half
//     (rows 1023..512 -> rev-alpha). RUN_HALF machinery byte-identical to
//     R19 (absmax 0.0). Final state (aE,aO,e,aZ x 64 lanes = 256 floats)
//     -> d_ws[bid*256].
//   kernel 2 (ctc_meet, 256 x 64): R19's verified junction
//     P = sum_s alpha[s] * sum_{s' in succ(s)} b'[s'], states from d_ws.
// d_ws usage: 512*256*4B = 512 KB.
// Prediction: per-wave cadence -> kernel1 ~30us, bench ~172. Per-CU
// aggregate -> null (~198). absmax 0.0 either way.

#define B_     256
#define T_     1024
#define C_     128
#define L_     64
#define BLANK_ 127
#define LN2_   0.69314718055994530942f
#define ROWS   32
#define LDSF   (ROWS * C_)      // 4096 floats = 16 KB per slot

__device__ __forceinline__ float flog2(float x) { return __builtin_amdgcn_logf(x); }

template <int CTRL>
__device__ __forceinline__ int dpp_i(int x) {
    return __builtin_amdgcn_update_dpp(x, x, CTRL, 0xF, 0xF, false);
}
// wave rotate right: lane i receives lane (i-1)&63
__device__ __forceinline__ float ror1_f(float x) {
    return __int_as_float(dpp_i<0x13C>(__float_as_int(x)));
}
__device__ __forceinline__ int ror1_i(int x) { return dpp_i<0x13C>(x); }

__device__ __forceinline__ float fldexp(float x, int n) {
#if __has_builtin(__builtin_amdgcn_ldexpf)
    return __builtin_amdgcn_ldexpf(x, n);
#else
    return ldexpf(x, n);
#endif
}
// frexp-style exponent; 0 for x==0
__device__ __forceinline__ int fexp_of(float x) {
#if __has_builtin(__builtin_amdgcn_frexp_expf)
    return __builtin_amdgcn_frexp_expf(x);
#else
    const int bx = (__float_as_int(x) >> 23) & 0xFF;
    return (x > 0.0f) ? (bx - 126) : 0;
#endif
}

typedef const __attribute__((address_space(1))) void gas_void;
typedef __attribute__((address_space(3))) void las_void;
__device__ __forceinline__ void g2l16(const float* g, float* l) {
    __builtin_amdgcn_global_load_lds((gas_void*)g, (las_void*)l, 16, 0, 0);
}

// ---- verified forward machinery (R14/R16/R19, absmax 0.0) ----
#define ALSTEP(pL, pB)                                                        \
    {                                                                         \
        const int   ep  = ror1_i(e);                                          \
        const float mpO = ror1_f(aO);                                         \
        const bool dead = (fmaxf(aE, aO) == 0.0f);                            \
        e = dead ? ep : e;                                                    \
        const int   dd  = ep - e;                                             \
        float prevO = fldexp(mpO, dd);                                        \
        prevO = isL0 ? 0.0f : prevO;                                          \
        const float sk = can_skip ? prevO : 0.0f;                             \
        const float nE = (aE + prevO) * (pB);                                 \
        const float nO = (aO + aE + sk) * (pL);                               \
        aZ = (aZ + aO) * (pB);                                                \
        aE = nE; aO = nO;                                                     \
    }

#define RENORM4                                                               \
    {                                                                         \
        const int x = fexp_of(fmaxf(aE, aO));                                 \
        aE = fldexp(aE, -x); aO = fldexp(aO, -x); aZ = fldexp(aZ, -x);        \
        e += x;                                                               \
    }

#define DCALC                                                                 \
    {                                                                         \
        const int ep = ror1_i(e);                                             \
        d = isL0 ? (-16384) : (ep - e);                                       \
    }

#define RENORM4B { RENORM4 DCALC }

#define BLSTEP(pL, pB)                                                        \
    {                                                                         \
        const float prevO = fldexp(ror1_f(aO), d);                            \
        const float nE = (aE + prevO) * (pB);                                 \
        const float nO = __builtin_fmaf(skf, prevO, aO + aE) * (pL);          \
        aZ = (aZ + aO) * (pB);                                                \
        aE = nE; aO = nO;                                                     \
    }

#define ACHUNK(RL, RB)                                                        \
    {                                                                         \
        _Pragma("unroll")                                                     \
        for (int k = 0; k < 32; ++k) {                                        \
            ALSTEP(RL[k], RB[k])                                              \
            if ((k & 3) == 3) RENORM4                                         \
        }                                                                     \
    }

#define BCHUNK32(RL, RB)                                                      \
    {                                                                         \
        _Pragma("unroll")                                                     \
        for (int k = 0; k < 32; ++k) {                                        \
            BLSTEP(RL[k], RB[k])                                              \
            if ((k & 3) == 3) RENORM4B                                        \
        }                                                                     \
    }

#define STAGE16(ROW, LOFF)                                                    \
    {                                                                         \
        const float* src = base + (size_t)(ROW) * C_;                         \
        _Pragma("unroll")                                                     \
        for (int j = 0; j < 16; ++j)                                          \
            g2l16(src + j * 256 + lane * 4, sm + (LOFF) + j * 256);           \
    }

#define FBURSTM(LOFF, RL, RB)                                                 \
    {                                                                         \
        const float* pl = &sm[(LOFF) + lab];                                  \
        const float* pb = &sm[(LOFF) + BLANK_];                               \
        _Pragma("unroll")                                                     \
        for (int j = 0; j < 32; ++j) RL[j] = pl[j * C_];                      \
        _Pragma("unroll")                                                     \
        for (int j = 0; j < 32; ++j) RB[j] = pb[j * C_];                      \
    }
#define RBURSTM(LOFF, RL, RB)                                                 \
    {                                                                         \
        const float* pl = &sm[(LOFF) + lab];                                  \
        const float* pb = &sm[(LOFF) + BLANK_];                               \
        _Pragma("unroll")                                                     \
        for (int j = 0; j < 32; ++j) RL[j] = pl[(31 - j) * C_];               \
        _Pragma("unroll")                                                     \
        for (int j = 0; j < 32; ++j) RB[j] = pb[(31 - j) * C_];               \
    }

#define VMWAIT asm volatile("s_waitcnt vmcnt(0)" ::: "memory")

// 511-step half (R19-verbatim): phase A chunks 0..3, phase B chunks 4..15.
#define RUN_HALF(CHUNKROW, BURSTM)                                            \
    {                                                                         \
        float rl0[32], rb0[32], rl1[32], rb1[32];                             \
        STAGE16(CHUNKROW(0), 0)                                               \
        STAGE16(CHUNKROW(1), LDSF)                                            \
        aE = isL0 ? ibase[BLANK_] : 0.0f;                                     \
        aO = isL0 ? ibase[lab]    : 0.0f;                                     \
        VMWAIT;                                                               \
        BURSTM(0, rl0, rb0)                       /* chunk 0 */               \
        STAGE16(CHUNKROW(2), 2 * LDSF)                                        \
        BURSTM(LDSF, rl1, rb1)                    /* chunk 1 */               \
        ACHUNK(rl0, rb0)                                                      \
        VMWAIT;                                                               \
        STAGE16(CHUNKROW(3), 0)                                               \
        BURSTM(2 * LDSF, rl0, rb0)                /* chunk 2 */               \
        ACHUNK(rl1, rb1)                                                      \
        VMWAIT;                                                               \
        STAGE16(CHUNKROW(4), LDSF)                                            \
        BURSTM(0, rl1, rb1)                       /* chunk 3 */               \
        ACHUNK(rl0, rb0)                                                      \
        VMWAIT;                                                               \
        STAGE16(CHUNKROW(5), 2 * LDSF)                                        \
        BURSTM(LDSF, rl0, rb0)                    /* chunk 4 */               \
        ACHUNK(rl1, rb1)                                                      \
        VMWAIT;                                                               \
        DCALC                                                                 \
        _Pragma("unroll 1")                                                   \
        for (int c = 4; c <= 12; c += 2) {                                    \
            STAGE16(CHUNKROW(c + 2), ((c + 2) % 3) * LDSF)                    \
            BURSTM(((c + 1) % 3) * LDSF, rl1, rb1)                            \
            BCHUNK32(rl0, rb0)                                                \
            VMWAIT;                                                           \
            STAGE16(CHUNKROW(c + 3), ((c + 3) % 3) * LDSF)                    \
            BURSTM(((c + 2) % 3) * LDSF, rl0, rb0)                            \
            BCHUNK32(rl1, rb1)                                                \
            VMWAIT;                                                           \
        }                                                                     \
        BURSTM(0, rl1, rb1)                       /* chunk 15, slot 0 */      \
        BCHUNK32(rl0, rb0)                        /* chunk 14 */              \
        _Pragma("unroll")                                                     \
        for (int k = 0; k < 31; ++k) {            /* chunk 15: 31 steps */    \
            BLSTEP(rl1[k], rb1[k])                                            \
            if ((k & 3) == 3) RENORM4B                                        \
        }                                                                     \
    }

#define FROW(k) (1 + 32 * (k))
#define RROW(k) (991 - 32 * (k))

#define ACCP(t, Et)                                                           \
    {                                                                         \
        const float t_ = (t); const int Et_ = (Et);                           \
        const int Em = (Eacc > Et_) ? Eacc : Et_;                             \
        acc = fldexp(acc, Eacc - Em) + fldexp(t_, Et_ - Em);                  \
        Eacc = Em;                                                            \
    }

// ===== kernel 1: 512 blocks; block 2b = fwd half, 2b+1 = reversed half ====
__global__ __launch_bounds__(64, 1)
void ctc_halves(const int* __restrict__ yt, const float* __restrict__ yp,
                float* __restrict__ ws) {
    __shared__ float sm[3 * LDSF];                // 48 KB, 3-slot rotation

    const int bid  = blockIdx.x;
    const int b    = bid >> 1;
    const int dir  = bid & 1;
    const int lane = threadIdx.x;
    const int lidx = dir ? (63 - lane) : lane;
    const int lab  = yt[b * L_ + lidx];
    const int labp = __shfl_up(lab, 1);
    const bool can_skip = (lane > 0) && (lab != labp);
    const bool isL0     = (lane == 0);
    const float skf     = can_skip ? 1.0f : 0.0f;

    const float* __restrict__ base  = yp + (size_t)b * T_ * C_;
    const float* __restrict__ ibase = dir ? (base + 1023 * C_) : base;

    float aE = 0.0f, aO = 0.0f, aZ = 0.0f;
    int   e  = 0, d = 0;

    if (dir == 0) {
        RUN_HALF(FROW, FBURSTM)                   // rows 0..511 -> alpha_511
    } else {
        RUN_HALF(RROW, RBURSTM)                   // rows 1023..512 -> rev-alpha
    }

    float* w4 = ws + (size_t)bid * 256;
    w4[lane]        = aE;
    w4[64 + lane]   = aO;
    w4[128 + lane]  = __int_as_float(e);
    w4[192 + lane]  = aZ;
}

// ===== kernel 2: junction meet (R19-verified math, states from ws) ========
__global__ __launch_bounds__(64, 1)
void ctc_meet(const int* __restrict__ yt, const float* __restrict__ ws,
              float* __restrict__ out) {
    const int b    = blockIdx.x;
    const int lane = threadIdx.x;
    const int i    = lane;
    const bool isL0  = (lane == 0);
    const bool isL63 = (lane == 63);

    const float* wf = ws + (size_t)(2 * b) * 256;
    const float* wr = wf + 256;

    const float aE = wf[lane];
    const float aO = wf[64 + lane];
    const int   e  = __float_as_int(wf[128 + lane]);
    const float aZ = wf[192 + lane];              // only lane 63's is used

    const int lab  = yt[b * L_ + lane];
    const int labn = __shfl_down(lab, 1);
    const float sknE = (!isL63 && labn != lab) ? 1.0f : 0.0f;

    // b'[s'] = rev-alpha[128-s'] * 2^e_rev
    const float rE_hi = isL0 ? wr[192 + 63] : wr[64 - i];
    const int   e_hi  = __float_as_int(isL0 ? wr[128 + 63] : wr[128 + 64 - i]);
    const float rO_hi = wr[64 + 63 - i];
    const int   eo_hi = __float_as_int(wr[128 + 63 - i]);
    const float rE_nx = isL63 ? wr[0] : wr[63 - i];
    const int   e_nx  = __float_as_int(isL63 ? wr[128] : wr[128 + 63 - i]);
    const float rO_nx = isL63 ? 0.0f : wr[64 + 62 - i];
    const int   eo_nx = isL63 ? 0 : __float_as_int(wr[128 + 62 - i]);

    float acc = aE * rE_hi;
    int  Eacc = e + e_hi;
    ACCP((aE + aO) * rO_hi, e + eo_hi)
    ACCP((isL63 ? (aO + aZ) : aO) * rE_nx, e + e_nx)
    ACCP(sknE * (aO * rO_nx), e + eo_nx)
    if (acc == 0.0f) Eacc = -(1 << 29);

#pragma unroll
    for (int off = 1; off < 64; off <<= 1) {
        const float s2 = __shfl_xor(acc, off);
        const int   E2 = __shfl_xor(Eacc, off);
        const int   Em = (Eacc > E2) ? Eacc : E2;
        acc = fldexp(acc, Eacc - Em) + fldexp(s2, E2 - Em);
        Eacc = Em;
    }
    if (lane == 0) out[b] = -(flog2(acc) + (float)Eacc) * LN2_;
}

extern "C" void kernel_launch(void* const* d_in, const int* in_sizes, int n_in,
                              void* d_out, int out_size, void* d_ws, size_t ws_size,
                              hipStream_t stream) {
    const int*   y_true = (const int*)d_in[0];
    const float* y_pred = (const float*)d_in[1];
    float*       out    = (float*)d_out;
    float*       ws     = (float*)d_ws;          // needs 512 KB
    ctc_halves<<<2 * B_, 64, 0, stream>>>(y_true, y_pred, ws);
    ctc_meet<<<B_, 64, 0, stream>>>(y_true, ws, out);
}

// Round 13
// 196.500 us; speedup vs baseline: 1.0093x; 1.0093x over previous
//
#include <hip/hip_runtime.h>

// CTC forward loss, B=256, T=1024, C=128, L=64, S=2L+1=129, BLANK=127.
// One wave per batch element (256 blocks x 64 threads).
//
// Round 21: INSTRUCTION DIET v2 (packed fp32 + renorm-8).
// Law fitting R8-R20 (incl. three bisection nulls): kernel time ~= per-CU
// aggregate dynamic instrs x ~9cyc, independent of wave count / deps /
// memory path. Per-CU step count is CONSERVED under any bisection
// (256 batches / 256 CUs) -- only reducing instructions helps (R12->R14:
// 85.5 -> ~60us tracked the instr cut).
//  - Pack (aE, aZ) as float2 ez; keep aO in po.y, prevO written to po.x:
//    nE/aZ updates become ONE pk_add + ONE pk_mul ({aE,aZ} + {prevO,aO},
//    then splat-mul by pB). Bit-identical arithmetic; 9 VALU -> 7 if
//    packed, 9 if compiler scalarizes (no regression).
//  - Phase B renorm every 8 steps (phase A keeps verified renorm-4 +
//    dead-lane adoption). Renorm is exact pow2 and d stays exact (e frozen
//    per window); only the FTZ-flush band widens (loses <2^-126-relative
//    contributions -- same accepted semantics, checker threshold 96).
// Everything else R16-verbatim (absmax 0.0): state remap, phase A t=1..128,
// 3-slot LDS rotation, global_load_lds w16, ONE vmcnt(0)/32 steps.

#define B_     256
#define T_     1024
#define C_     128
#define L_     64
#define BLANK_ 127
#define LN2_   0.69314718055994530942f
#define ROWS   32
#define LDSF   (ROWS * C_)      // 4096 floats = 16 KB per slot

typedef float f32x2 __attribute__((ext_vector_type(2)));

__device__ __forceinline__ float flog2(float x) { return __builtin_amdgcn_logf(x); }

template <int CTRL>
__device__ __forceinline__ int dpp_i(int x) {
    return __builtin_amdgcn_update_dpp(x, x, CTRL, 0xF, 0xF, false);
}
// wave rotate right: lane i receives lane (i-1)&63
__device__ __forceinline__ float ror1_f(float x) {
    return __int_as_float(dpp_i<0x13C>(__float_as_int(x)));
}
__device__ __forceinline__ int ror1_i(int x) { return dpp_i<0x13C>(x); }

__device__ __forceinline__ float fldexp(float x, int n) {
#if __has_builtin(__builtin_amdgcn_ldexpf)
    return __builtin_amdgcn_ldexpf(x, n);
#else
    return ldexpf(x, n);
#endif
}
// frexp-style exponent; 0 for x==0
__device__ __forceinline__ int fexp_of(float x) {
#if __has_builtin(__builtin_amdgcn_frexp_expf)
    return __builtin_amdgcn_frexp_expf(x);
#else
    const int bx = (__float_as_int(x) >> 23) & 0xFF;
    return (x > 0.0f) ? (bx - 126) : 0;
#endif
}

typedef const __attribute__((address_space(1))) void gas_void;
typedef __attribute__((address_space(3))) void las_void;
__device__ __forceinline__ void g2l16(const float* g, float* l) {
    __builtin_amdgcn_global_load_lds((gas_void*)g, (las_void*)l, 16, 0, 0);
}
__device__ __forceinline__ void g2l4(const float* g, float* l) {
    __builtin_amdgcn_global_load_lds((gas_void*)g, (las_void*)l, 4, 0, 0);
}

// ---- phase-A step (verified): per-step dead-lane adoption, scalars ----
#define ALSTEP(pL, pB)                                                        \
    {                                                                         \
        const int   ep  = ror1_i(e);                                          \
        const float mpO = ror1_f(aO);                                         \
        const bool dead = (fmaxf(aE, aO) == 0.0f);                            \
        e = dead ? ep : e;                                                    \
        const int   dd  = ep - e;                                             \
        float prevO = fldexp(mpO, dd);                                        \
        prevO = isL0 ? 0.0f : prevO;                                          \
        const float sk = can_skip ? prevO : 0.0f;                             \
        const float nE = (aE + prevO) * (pB);                                 \
        const float nO = (aO + aE + sk) * (pL);                               \
        aZ = (aZ + aO) * (pB);                                                \
        aE = nE; aO = nO;                                                     \
    }

#define RENORM4                                                               \
    {                                                                         \
        const int x = fexp_of(fmaxf(aE, aO));                                 \
        aE = fldexp(aE, -x); aO = fldexp(aO, -x); aZ = fldexp(aZ, -x);        \
        e += x;                                                               \
    }

#define DCALC                                                                 \
    {                                                                         \
        const int ep = ror1_i(e);                                             \
        d = isL0 ? (-16384) : (ep - e);                                       \
    }

// ---- phase-B packed step: ez = {aE, aZ}, po = {prevO, aO} ----
// nE = (aE+prevO)*pB ; aZ' = (aZ+aO)*pB  -> pk_add + splat pk_mul
// nO = fma(skf, prevO, aE+aO)*pL         -> written into po.y
// Bit-identical per-step arithmetic to R16's BLSTEP.
#define BLSTEP8(pL, pB)                                                       \
    {                                                                         \
        const float m = ror1_f(po.y);                                         \
        po.x = fldexp(m, d);                                                  \
        const float s_ = ez.x + po.y;                                         \
        ez = ez + po;                                                         \
        ez = ez * (pB);                                                       \
        po.y = __builtin_fmaf(skf, po.x, s_) * (pL);                          \
    }

// renorm every 8 steps + refresh window alignment d
#define RENORM8B                                                              \
    {                                                                         \
        const int x = fexp_of(fmaxf(ez.x, po.y));                             \
        ez.x = fldexp(ez.x, -x); ez.y = fldexp(ez.y, -x);                     \
        po.y = fldexp(po.y, -x);                                              \
        e += x;                                                               \
        const int ep = ror1_i(e);                                             \
        d = isL0 ? (-16384) : (ep - e);                                       \
    }

#define ACHUNK(RL, RB)                                                        \
    {                                                                         \
        _Pragma("unroll")                                                     \
        for (int k = 0; k < 32; ++k) {                                        \
            ALSTEP(RL[k], RB[k])                                              \
            if ((k & 3) == 3) RENORM4                                         \
        }                                                                     \
    }

#define BCHUNK32P(RL, RB)                                                     \
    {                                                                         \
        _Pragma("unroll")                                                     \
        for (int k = 0; k < 32; ++k) {                                        \
            BLSTEP8(RL[k], RB[k])                                             \
            if ((k & 7) == 7) RENORM8B                                        \
        }                                                                     \
    }

// Stage chunk k (rows t = 1+32k .. 32+32k; k==31 -> final 31 rows).
#define STAGE_CHUNK(k, LOFF)                                                  \
    {                                                                         \
        const float* src = base + (size_t)(1 + 32 * (k)) * C_;                \
        const int nKB = ((k) == 31) ? 15 : 16;                                \
        _Pragma("unroll")                                                     \
        for (int j = 0; j < 16; ++j)                                          \
            if (j < nKB)                                                      \
                g2l16(src + j * 256 + lane * 4, sm + (LOFF) + j * 256);       \
        if ((k) == 31) {                                                      \
            const float* s2 = src + 15 * 256;                                 \
            g2l4(s2 + lane,      sm + (LOFF) + 15 * 256);                     \
            g2l4(s2 + 64 + lane, sm + (LOFF) + 15 * 256 + 64);                \
        }                                                                     \
    }

// Burst: split loops, one vaddr + immediate offsets each.
#define BURST(LOFF, RL, RB, NR)                                               \
    {                                                                         \
        const float* pl = &sm[(LOFF) + lab];                                  \
        const float* pb = &sm[(LOFF) + BLANK_];                               \
        _Pragma("unroll")                                                     \
        for (int j = 0; j < (NR); ++j) RL[j] = pl[j * C_];                    \
        _Pragma("unroll")                                                     \
        for (int j = 0; j < (NR); ++j) RB[j] = pb[j * C_];                    \
    }

#define VMWAIT asm volatile("s_waitcnt vmcnt(0)" ::: "memory")

__global__ __launch_bounds__(64, 1)
void ctc_fwd(const int* __restrict__ yt, const float* __restrict__ yp,
             float* __restrict__ out) {
    __shared__ float sm[3 * LDSF];                // 48 KB, 3-slot rotation

    const int b    = blockIdx.x;
    const int lane = threadIdx.x;                 // 0..63
    const int lab  = yt[b * L_ + lane];           // label of state 2*lane+1
    const int labp = __shfl_up(lab, 1);           // init-only
    const bool can_skip = (lane > 0) && (lab != labp);
    const bool isL0     = (lane == 0);
    const float skf     = can_skip ? 1.0f : 0.0f;

    const float* __restrict__ base = yp + (size_t)b * T_ * C_;

    // ---- prologue: stage chunks 0 and 1 ----
    STAGE_CHUNK(0, 0)
    STAGE_CHUNK(1, LDSF)

    // ---- t=0 init: state 0 = lane0.aE, state 1 = lane0.aO ----
    float aE = isL0 ? base[BLANK_] : 0.0f;
    float aO = isL0 ? base[lab]    : 0.0f;
    float aZ = 0.0f;                              // state 128 (lane 63)
    int   e  = 0, d = 0;

    VMWAIT;                                       // slots 0,1 + init loads

    float rl0[32], rb0[32], rl1[32], rb1[32];
    BURST(0, rl0, rb0, 32)                        // chunk 0

    // ---- phase A: chunks 0..3 (t = 1..128), per-step adoption ----
    STAGE_CHUNK(2, 2 * LDSF)
    BURST(LDSF, rl1, rb1, 32)                     // chunk 1
    ACHUNK(rl0, rb0)                              // t 1..32
    VMWAIT;

    STAGE_CHUNK(3, 0)
    BURST(2 * LDSF, rl0, rb0, 32)                 // chunk 2
    ACHUNK(rl1, rb1)                              // t 33..64
    VMWAIT;

    STAGE_CHUNK(4, LDSF)
    BURST(0, rl1, rb1, 32)                        // chunk 3
    ACHUNK(rl0, rb0)                              // t 65..96
    VMWAIT;

    STAGE_CHUNK(5, 2 * LDSF)
    BURST(LDSF, rl0, rb0, 32)                     // chunk 4
    ACHUNK(rl1, rb1)                              // t 97..128
    VMWAIT;

    // ---- phase A -> B: pack state, first window alignment ----
    f32x2 ez, po;
    ez.x = aE; ez.y = aZ;
    po.x = 0.0f; po.y = aO;
    DCALC

    // ---- phase B: chunks 4..29 in pairs (t = 129..960) ----
#pragma unroll 1
    for (int c = 4; c <= 28; c += 2) {
        {   // compute chunk c (regs 0); burst c+1; stage c+2
            STAGE_CHUNK(c + 2, ((c + 2) % 3) * LDSF)
            BURST(((c + 1) % 3) * LDSF, rl1, rb1, 32)
            BCHUNK32P(rl0, rb0)
            VMWAIT;
        }
        {   // compute chunk c+1 (regs 1); burst c+2; stage c+3
            STAGE_CHUNK(c + 3, ((c + 3) % 3) * LDSF)
            BURST(((c + 2) % 3) * LDSF, rl0, rb0, 32)
            BCHUNK32P(rl1, rb1)
            VMWAIT;
        }
    }

    // ---- chunk 30 (t = 961..992); burst chunk 31 (slot 31%3=1) ----
    BURST((31 % 3) * LDSF, rl1, rb1, 31)
    BCHUNK32P(rl0, rb0)

    // ---- chunk 31: t = 993..1023 (31 steps) ----
#pragma unroll
    for (int k = 0; k < 31; ++k) {
        BLSTEP8(rl1[k], rb1[k])
        if ((k & 7) == 7) RENORM8B
    }

    // loss = -ln(alpha[127] + alpha[128]); aO=po.y, aZ=ez.y share scale 2^e.
    if (lane == 63) {
        const float s = po.y + ez.y;
        out[b] = -(flog2(s) + (float)e) * LN2_;
    }
}

extern "C" void kernel_launch(void* const* d_in, const int* in_sizes, int n_in,
                              void* d_out, int out_size, void* d_ws, size_t ws_size,
                              hipStream_t stream) {
    const int*   y_true = (const int*)d_in[0];
    const float* y_pred = (const float*)d_in[1];
    float*       out    = (float*)d_out;
    ctc_fwd<<<B_, 64, 0, stream>>>(y_true, y_pred, out);
}